// Round 2
// baseline (152.124 us; speedup 1.0000x reference)
//
#include <hip/hip_runtime.h>

typedef short bf16x8 __attribute__((ext_vector_type(8)));
typedef float f32x4 __attribute__((ext_vector_type(4)));
typedef unsigned u32x4 __attribute__((ext_vector_type(4)));
typedef unsigned u32x2 __attribute__((ext_vector_type(2)));
typedef unsigned short ushort_t;

#define RS 2048          // fp32 tensor row stride (elements)
#define LDSK 72          // padded LDS row stride (shorts) for prep/fallback
#define PSTR 40          // Psh row stride (shorts): 80B rows, 16B-aligned reads
#define QSCALE 0.18033688011f   // 0.125 * log2(e)
#define BH_STRIDE (2048*64)     // shorts per bh plane in Kbf / Vtb

// pack two floats -> two bf16 (round-half-up) in one u32
static __device__ __forceinline__ unsigned pkbf(float a, float b) {
    union { float f; unsigned u; } ua, ub; ua.f = a; ub.f = b;
    return ((ua.u + 0x8000u) >> 16) | ((ub.u + 0x8000u) & 0xffff0000u);
}

static __device__ __forceinline__ float fexp2(float x) {
#if __has_builtin(__builtin_amdgcn_exp2f)
    return __builtin_amdgcn_exp2f(x);
#else
    return exp2f(x);
#endif
}

// async global->LDS, 16B per lane; LDS dest = wave-uniform base + lane*16
static __device__ __forceinline__ void gload16(const ushort_t* g, short* l) {
    __builtin_amdgcn_global_load_lds(
        (const __attribute__((address_space(1))) unsigned int*)(g),
        (__attribute__((address_space(3))) unsigned int*)(l), 16, 0, 0);
}

// ---------------- prep: fp32 K,V -> bf16 Kbf[bh][key][d], Vtb[bh][d][key] ----------------
__global__ __launch_bounds__(256)
void prep_bf16(const float* __restrict__ K, const float* __restrict__ V,
               ushort_t* __restrict__ Kbf, ushort_t* __restrict__ Vtb)
{
    __shared__ short Tt[64 * LDSK];
    const int kt = blockIdx.x, bh = blockIdx.y;
    const int t = threadIdx.x;

    // K phase: 64 keys x 64 d, coalesced read, contiguous bf16 write
    {
        const int key = t >> 2, cq = (t & 3) * 16;
        const float* kp = K + (size_t)(kt * 64 + key) * RS + bh * 64 + cq;
        f32x4 a0 = *(const f32x4*)kp,     a1 = *(const f32x4*)(kp + 4);
        f32x4 a2 = *(const f32x4*)(kp + 8), a3 = *(const f32x4*)(kp + 12);
        u32x4 w0, w1;
        w0[0] = pkbf(a0[0], a0[1]); w0[1] = pkbf(a0[2], a0[3]);
        w0[2] = pkbf(a1[0], a1[1]); w0[3] = pkbf(a1[2], a1[3]);
        w1[0] = pkbf(a2[0], a2[1]); w1[1] = pkbf(a2[2], a2[3]);
        w1[2] = pkbf(a3[0], a3[1]); w1[3] = pkbf(a3[2], a3[3]);
        ushort_t* kout = Kbf + (size_t)bh * BH_STRIDE + (size_t)(kt * 64 + key) * 64 + cq;
        *(u32x4*)kout = w0;
        *(u32x4*)(kout + 8) = w1;
    }
    // V phase: transpose 64 keys x 64 d via LDS (key-pairs packed per u32)
    {
        const int vkey = (t & 31) * 2, vd = (t >> 5) * 8;
        const float* vp = V + (size_t)(kt * 64 + vkey) * RS + bh * 64 + vd;
        f32x4 b0 = *(const f32x4*)vp,        b1 = *(const f32x4*)(vp + 4);
        f32x4 c0 = *(const f32x4*)(vp + RS), c1 = *(const f32x4*)(vp + RS + 4);
        #pragma unroll
        for (int i = 0; i < 4; ++i) {
            *(unsigned*)&Tt[(vd + i) * LDSK + vkey]     = pkbf(b0[i], c0[i]);
            *(unsigned*)&Tt[(vd + 4 + i) * LDSK + vkey] = pkbf(b1[i], c1[i]);
        }
    }
    __syncthreads();
    {
        // write-back: 64 d-rows x 64 keys; each thread writes two 16B chunks
        const int d = t >> 2, kq = (t & 3) * 16;
        ushort_t* vout = Vtb + (size_t)bh * BH_STRIDE + (size_t)d * RS + kt * 64 + kq;
        u32x4 w0 = *(const u32x4*)&Tt[d * LDSK + kq];
        u32x4 w1 = *(const u32x4*)&Tt[d * LDSK + kq + 8];
        *(u32x4*)vout = w0;
        *(u32x4*)(vout + 8) = w1;
    }
}

// ---------------- main: flash attention, split-K job schedule ----------------
// Job table (makespan fix): per-CU makespan was max-block-length = 32 tiles even
// though avg work/slot is 16.5. Cap job length at 16 by splitting qt>=16 rows'
// key range in half; halves write unnormalized partials (pO, pL), combined by
// the combine kernel. Dispatch order is LPT-ish (long jobs first).
__global__ __launch_bounds__(256, 4)
void fa_fwd4(const float* __restrict__ Q, const ushort_t* __restrict__ Kbf,
             const ushort_t* __restrict__ Vtb, float* __restrict__ Out,
             float* __restrict__ pO, float* __restrict__ pL)
{
    __shared__ alignas(16) short Kd[2][4096];
    __shared__ alignas(16) short Vd[2][4096];
    __shared__ alignas(16) short Psh[4][16 * PSTR];

    // ---- decode job from blockIdx ----
    const int x = blockIdx.x;
    int qt, bh, kt0, kt1, pslot = 0;
    bool hasdiag, direct;
    if (x < 512) {                       // halves, qt 31..24 (len 12-16)
        const int i = x; qt = 31 - (i >> 6); bh = (i >> 1) & 31;
        const int half = i & 1, mid = (qt + 1) >> 1;
        kt0 = half ? mid : 0; kt1 = half ? qt : (mid - 1);
        hasdiag = half; direct = false;
        pslot = ((qt - 16) * 32 + bh) * 2 + half;
    } else if (x < 768) {                // shorts, qt 15..8 (len 9-16)
        const int i = x - 512; qt = 15 - (i >> 5); bh = i & 31;
        kt0 = 0; kt1 = qt; hasdiag = true; direct = true;
    } else if (x < 1280) {               // halves, qt 23..16 (len 8-12)
        const int i = x - 768; qt = 23 - (i >> 6); bh = (i >> 1) & 31;
        const int half = i & 1, mid = (qt + 1) >> 1;
        kt0 = half ? mid : 0; kt1 = half ? qt : (mid - 1);
        hasdiag = half; direct = false;
        pslot = ((qt - 16) * 32 + bh) * 2 + half;
    } else {                             // shorts, qt 7..0 (len 1-8)
        const int i = x - 1280; qt = 7 - (i >> 5); bh = i & 31;
        kt0 = 0; kt1 = qt; hasdiag = true; direct = true;
    }

    const int base = bh * 64;
    const int tid = threadIdx.x;
    const int wave = tid >> 6;
    const int n15 = tid & 15, quad = (tid & 63) >> 4;
    const int q0 = qt * 64;

    // staging source mapping: thread tid handles tile chunks tid and tid+256.
    // chunk c: row=c>>3, slot=c&7, content group g = slot ^ (row&7)  (rule 21:
    // inverse-swizzled global source + linear gload_lds dest + swizzled read).
    const int srow = tid >> 3, sg = (tid & 7) ^ (srow & 7);
    const ushort_t* kb2 = Kbf + (size_t)bh * BH_STRIDE + srow * 64 + sg * 8;
    const ushort_t* vb2 = Vtb + (size_t)bh * BH_STRIDE + (size_t)srow * RS + sg * 8;

    auto stage = [&](int buf, int kt) {
        const ushort_t* ks = kb2 + (size_t)kt * 4096;
        const ushort_t* vs = vb2 + kt * 64;
        short* kd = &Kd[buf][wave * 512];
        short* vd = &Vd[buf][wave * 512];
        gload16(ks,         kd);
        gload16(ks + 2048,  kd + 2048);   // rows +32 -> chunks +256
        gload16(vs,         vd);
        gload16(vs + 65536, vd + 2048);   // d +32 (32*RS shorts)
    };

    stage(0, kt0);   // first-tile loads in flight while we set up Q

    // Q fragment (B operand of S^T = K.Q^T), pre-scaled into log2 domain
    bf16x8 qf[2];
    {
        const float* qp = Q + (size_t)(q0 + wave * 16 + n15) * RS + base + quad * 8;
        #pragma unroll
        for (int ks = 0; ks < 2; ++ks) {
            f32x4 a0 = *(const f32x4*)(qp + ks * 32) * QSCALE;
            f32x4 a1 = *(const f32x4*)(qp + ks * 32 + 4) * QSCALE;
            union { u32x4 u; bf16x8 s; } w;
            w.u[0] = pkbf(a0[0], a0[1]); w.u[1] = pkbf(a0[2], a0[3]);
            w.u[2] = pkbf(a1[0], a1[1]); w.u[3] = pkbf(a1[2], a1[3]);
            qf[ks] = w.s;
        }
    }

    f32x4 O[4];
    #pragma unroll
    for (int i = 0; i < 4; ++i) O[i] = (f32x4){0.f, 0.f, 0.f, 0.f};
    float l = 0.f;

    // swizzled ds_read column offsets (shorts)
    const int c0 = (quad * 8) ^ ((n15 & 7) * 8);
    const int c1 = c0 ^ 32;

    asm volatile("s_waitcnt vmcnt(0)" ::: "memory");
    __builtin_amdgcn_sched_barrier(0);
    __builtin_amdgcn_s_barrier();

    int buf = 0;
    for (int kt = kt0; kt <= kt1; ++kt) {
        if (kt < kt1) stage(buf ^ 1, kt + 1);   // async loads fly under compute
        const short* Kb_ = Kd[buf];
        const short* Vb_ = Vd[buf];

        // QK^T -> S^T tile: row = key = mb*16+quad*4+r, col = q = n15
        f32x4 S[4];
        __builtin_amdgcn_s_setprio(1);
        #pragma unroll
        for (int mb = 0; mb < 4; ++mb) {
            const short* kr = Kb_ + (mb * 16 + n15) * 64;
            bf16x8 kf0 = *(const bf16x8*)(kr + c0);
            bf16x8 kf1 = *(const bf16x8*)(kr + c1);
            f32x4 sv = (f32x4){0.f, 0.f, 0.f, 0.f};
            sv = __builtin_amdgcn_mfma_f32_16x16x32_bf16(kf0, qf[0], sv, 0, 0, 0);
            sv = __builtin_amdgcn_mfma_f32_16x16x32_bf16(kf1, qf[1], sv, 0, 0, 0);
            S[mb] = sv;
        }
        __builtin_amdgcn_s_setprio(0);

        if (hasdiag && kt == qt) {
            const int kb_ = kt * 64;
            const int q = q0 + wave * 16 + n15;
            #pragma unroll
            for (int mb = 0; mb < 4; ++mb)
                #pragma unroll
                for (int r = 0; r < 4; ++r)
                    if (kb_ + mb * 16 + quad * 4 + r > q) S[mb][r] = -1e30f;
        }

        // softmax + P staging per 32-key half (Psh half-size, reused; DS ops
        // are in-order per wave so half-0's read completes before overwrite)
        float rs = 0.f;
        bf16x8 pf[2];
        #pragma unroll
        for (int half = 0; half < 2; ++half) {
            #pragma unroll
            for (int m2 = 0; m2 < 2; ++m2) {
                f32x4 sv = S[half * 2 + m2];
                float p0 = fexp2(sv[0]), p1 = fexp2(sv[1]);
                float p2 = fexp2(sv[2]), p3 = fexp2(sv[3]);
                rs += (p0 + p1) + (p2 + p3);
                unsigned w0, w1;
                asm("v_cvt_pk_bf16_f32 %0, %1, %2" : "=v"(w0) : "v"(p0), "v"(p1));
                asm("v_cvt_pk_bf16_f32 %0, %1, %2" : "=v"(w1) : "v"(p2), "v"(p3));
                u32x2 w; w[0] = w0; w[1] = w1;
                *(u32x2*)&Psh[wave][n15 * PSTR + m2 * 16 + quad * 4] = w;
            }
            pf[half] = *(const bf16x8*)&Psh[wave][n15 * PSTR + quad * 8];
        }
        rs += __shfl_xor(rs, 16);
        rs += __shfl_xor(rs, 32);
        l += rs;

        // PV: O[q][d] += P[q][keys] * V^T[d][keys]
        __builtin_amdgcn_s_setprio(1);
        #pragma unroll
        for (int db = 0; db < 4; ++db) {
            const short* vr = Vb_ + (db * 16 + n15) * 64;
            bf16x8 vf0 = *(const bf16x8*)(vr + c0);
            O[db] = __builtin_amdgcn_mfma_f32_16x16x32_bf16(pf[0], vf0, O[db], 0, 0, 0);
            bf16x8 vf1 = *(const bf16x8*)(vr + c1);
            O[db] = __builtin_amdgcn_mfma_f32_16x16x32_bf16(pf[1], vf1, O[db], 0, 0, 0);
        }
        __builtin_amdgcn_s_setprio(0);

        if (kt < kt1) {
            asm volatile("s_waitcnt vmcnt(0)" ::: "memory");
            __builtin_amdgcn_sched_barrier(0);
            __builtin_amdgcn_s_barrier();
            buf ^= 1;
        }
    }

    if (direct) {
        #pragma unroll
        for (int r = 0; r < 4; ++r) {
            float inv = 1.0f / __shfl(l, quad * 4 + r);
            size_t row = (size_t)(q0 + wave * 16 + quad * 4 + r) * RS + base;
            #pragma unroll
            for (int db = 0; db < 4; ++db)
                Out[row + db * 16 + n15] = O[db][r] * inv;
        }
    } else {
        // unnormalized partials: pO[pslot][64 rows][64 d], pL[pslot][64 rows]
        float* po = pO + (size_t)pslot * 4096;
        #pragma unroll
        for (int r = 0; r < 4; ++r) {
            const int row = wave * 16 + quad * 4 + r;
            #pragma unroll
            for (int db = 0; db < 4; ++db)
                po[row * 64 + db * 16 + n15] = O[db][r];
        }
        // after the 2 shfl_xor's every lane holds the full row-sum for row
        // (wave*16 + n15); quad==0 lanes cover all 16 rows of the wave
        if (quad == 0) pL[pslot * 64 + wave * 16 + n15] = l;
    }
}

// ---------------- combine: Out = (pO_a + pO_b) / (pL_a + pL_b) ----------------
__global__ __launch_bounds__(256)
void fa_combine(const float* __restrict__ pO, const float* __restrict__ pL,
                float* __restrict__ Out)
{
    const int pair = blockIdx.x;                 // 512 pairs (qt 16..31 x 32 bh)
    const int qt = 16 + (pair >> 5), bh = pair & 31;
    const int tid = threadIdx.x;
    const int r = tid >> 2, c = (tid & 3) * 16;
    const float* a = pO + (size_t)(pair * 2) * 4096 + r * 64 + c;
    const float* b = a + 4096;
    const float inv = 1.0f / (pL[(pair * 2) * 64 + r] + pL[(pair * 2 + 1) * 64 + r]);
    float* o = Out + (size_t)(qt * 64 + r) * RS + bh * 64 + c;
    #pragma unroll
    for (int j = 0; j < 4; ++j) {
        f32x4 va = ((const f32x4*)a)[j];
        f32x4 vb = ((const f32x4*)b)[j];
        ((f32x4*)o)[j] = (va + vb) * inv;
    }
}

// ---------------- fallback (round-6 kernel) if ws is too small ----------------
__global__ __launch_bounds__(256, 3)
void fa_fwd_fb(const float* __restrict__ Q, const float* __restrict__ K,
               const float* __restrict__ V, float* __restrict__ Out)
{
    __shared__ short Ksh[2][64 * LDSK];
    __shared__ short Vt[2][64 * LDSK];
    __shared__ short Psh[4][16 * LDSK];

    const int qt = 31 - blockIdx.y;
    const int bh = blockIdx.x;
    const int base = bh * 64;
    const int tid = threadIdx.x;
    const int wave = tid >> 6, lane = tid & 63;
    const int n15 = lane & 15, quad = lane >> 4;
    const int q0 = qt * 64;
    const int krow = tid >> 2, kcg = (tid & 3) * 16;
    const int vkey = (tid & 31) * 2, vd = (tid >> 5) * 4;

    bf16x8 qf[2];
    {
        const float* qp = Q + (size_t)(q0 + wave * 16 + n15) * RS + base + quad * 8;
        #pragma unroll
        for (int ks = 0; ks < 2; ++ks) {
            f32x4 a0 = *(const f32x4*)(qp + ks * 32) * QSCALE;
            f32x4 a1 = *(const f32x4*)(qp + ks * 32 + 4) * QSCALE;
            union { u32x4 u; bf16x8 s; } w;
            w.u[0] = pkbf(a0[0], a0[1]); w.u[1] = pkbf(a0[2], a0[3]);
            w.u[2] = pkbf(a1[0], a1[1]); w.u[3] = pkbf(a1[2], a1[3]);
            qf[ks] = w.s;
        }
    }
    f32x4 O[4];
    #pragma unroll
    for (int i = 0; i < 4; ++i) O[i] = (f32x4){0.f, 0.f, 0.f, 0.f};
    float l = 0.f;
    f32x4 rk0, rk1, rk2, rk3, rv0, rv1, rv2, rv3;
    auto prefetch = [&](int kt) {
        const int kb = kt * 64;
        const float* kp = K + (size_t)(kb + krow) * RS + base + kcg;
        rk0 = *(const f32x4*)kp;       rk1 = *(const f32x4*)(kp + 4);
        rk2 = *(const f32x4*)(kp + 8); rk3 = *(const f32x4*)(kp + 12);
        const float* vp = V + (size_t)(kb + vkey) * RS + base + vd;
        rv0 = *(const f32x4*)vp;        rv1 = *(const f32x4*)(vp + RS);
        rv2 = *(const f32x4*)(vp + 32); rv3 = *(const f32x4*)(vp + RS + 32);
    };
    auto stage = [&](int buf) {
        u32x4 w0; w0[0] = pkbf(rk0[0], rk0[1]); w0[1] = pkbf(rk0[2], rk0[3]);
                  w0[2] = pkbf(rk1[0], rk1[1]); w0[3] = pkbf(rk1[2], rk1[3]);
        *(u32x4*)&Ksh[buf][krow * LDSK + kcg] = w0;
        u32x4 w1; w1[0] = pkbf(rk2[0], rk2[1]); w1[1] = pkbf(rk2[2], rk2[3]);
                  w1[2] = pkbf(rk3[0], rk3[1]); w1[3] = pkbf(rk3[2], rk3[3]);
        *(u32x4*)&Ksh[buf][krow * LDSK + kcg + 8] = w1;
        #pragma unroll
        for (int i = 0; i < 4; ++i) {
            *(unsigned*)&Vt[buf][(vd + i) * LDSK + vkey] = pkbf(rv0[i], rv1[i]);
            *(unsigned*)&Vt[buf][(vd + 32 + i) * LDSK + vkey] = pkbf(rv2[i], rv3[i]);
        }
    };
    auto compute = [&](int buf, int kb, bool diag) {
        f32x4 S[4];
        #pragma unroll
        for (int mb = 0; mb < 4; ++mb) {
            f32x4 sv = (f32x4){0.f, 0.f, 0.f, 0.f};
            bf16x8 kf0 = *(const bf16x8*)&Ksh[buf][(mb * 16 + n15) * LDSK + quad * 8];
            sv = __builtin_amdgcn_mfma_f32_16x16x32_bf16(kf0, qf[0], sv, 0, 0, 0);
            bf16x8 kf1 = *(const bf16x8*)&Ksh[buf][(mb * 16 + n15) * LDSK + 32 + quad * 8];
            sv = __builtin_amdgcn_mfma_f32_16x16x32_bf16(kf1, qf[1], sv, 0, 0, 0);
            S[mb] = sv;
        }
        if (diag) {
            int q = q0 + wave * 16 + n15;
            #pragma unroll
            for (int mb = 0; mb < 4; ++mb)
                #pragma unroll
                for (int r = 0; r < 4; ++r)
                    if (kb + mb * 16 + quad * 4 + r > q) S[mb][r] = -1e30f;
        }
        float rs = 0.f;
        #pragma unroll
        for (int mb = 0; mb < 4; ++mb) {
            float p0 = fexp2(S[mb][0]), p1 = fexp2(S[mb][1]);
            float p2 = fexp2(S[mb][2]), p3 = fexp2(S[mb][3]);
            rs += (p0 + p1) + (p2 + p3);
            u32x2 w; w[0] = pkbf(p0, p1); w[1] = pkbf(p2, p3);
            *(u32x2*)&Psh[wave][n15 * LDSK + mb * 16 + quad * 4] = w;
        }
        rs += __shfl_xor(rs, 16);
        rs += __shfl_xor(rs, 32);
        l += rs;
        bf16x8 pf0 = *(const bf16x8*)&Psh[wave][n15 * LDSK + quad * 8];
        bf16x8 pf1 = *(const bf16x8*)&Psh[wave][n15 * LDSK + 32 + quad * 8];
        #pragma unroll
        for (int db = 0; db < 4; ++db) {
            bf16x8 vf0 = *(const bf16x8*)&Vt[buf][(db * 16 + n15) * LDSK + quad * 8];
            O[db] = __builtin_amdgcn_mfma_f32_16x16x32_bf16(pf0, vf0, O[db], 0, 0, 0);
            bf16x8 vf1 = *(const bf16x8*)&Vt[buf][(db * 16 + n15) * LDSK + 32 + quad * 8];
            O[db] = __builtin_amdgcn_mfma_f32_16x16x32_bf16(pf1, vf1, O[db], 0, 0, 0);
        }
    };
    prefetch(0);
    stage(0);
    __syncthreads();
    for (int kt = 0; kt <= qt; ++kt) {
        const int cur = kt & 1;
        if (kt < qt) prefetch(kt + 1);
        compute(cur, kt * 64, kt == qt);
        if (kt < qt) stage(1 - cur);
        __syncthreads();
    }
    #pragma unroll
    for (int r = 0; r < 4; ++r) {
        float inv = 1.0f / __shfl(l, quad * 4 + r);
        size_t row = (size_t)(q0 + wave * 16 + quad * 4 + r) * RS + base;
        #pragma unroll
        for (int db = 0; db < 4; ++db)
            Out[row + db * 16 + n15] = O[db][r] * inv;
    }
}

extern "C" void kernel_launch(void* const* d_in, const int* in_sizes, int n_in,
                              void* d_out, int out_size, void* d_ws, size_t ws_size,
                              hipStream_t stream) {
    const float* Q = (const float*)d_in[0];
    const float* K = (const float*)d_in[1];
    const float* V = (const float*)d_in[2];
    float* Out = (float*)d_out;

    // ws layout: Kbf (8.39MB) | Vtb (8.39MB) | pO (16.78MB) | pL (256KB)
    const size_t kv_bytes = (size_t)2 * 32 * BH_STRIDE * sizeof(ushort_t);
    const size_t po_bytes = (size_t)1024 * 4096 * sizeof(float);
    const size_t pl_bytes = (size_t)1024 * 64 * sizeof(float);

    if (ws_size >= kv_bytes + po_bytes + pl_bytes) {
        ushort_t* Kbf = (ushort_t*)d_ws;
        ushort_t* Vtb = Kbf + (size_t)32 * BH_STRIDE;
        float* pO = (float*)((char*)d_ws + kv_bytes);
        float* pL = pO + (size_t)1024 * 4096;
        prep_bf16<<<dim3(32, 32), dim3(256), 0, stream>>>(K, V, Kbf, Vtb);
        fa_fwd4<<<dim3(1536), dim3(256), 0, stream>>>(Q, Kbf, Vtb, Out, pO, pL);
        fa_combine<<<dim3(512), dim3(256), 0, stream>>>(pO, pL, Out);
    } else {
        fa_fwd_fb<<<dim3(32, 32), dim3(256), 0, stream>>>(Q, K, V, Out);
    }
}

// Round 8
// 140.784 us; speedup vs baseline: 1.0806x; 1.0806x over previous
//
#include <hip/hip_runtime.h>

typedef short bf16x8 __attribute__((ext_vector_type(8)));
typedef float f32x4 __attribute__((ext_vector_type(4)));
typedef unsigned u32x4 __attribute__((ext_vector_type(4)));
typedef unsigned u32x2 __attribute__((ext_vector_type(2)));
typedef unsigned short ushort_t;

#define RS 2048          // fp32 tensor row stride (elements)
#define LDSK 72          // padded LDS row stride (shorts) for prep/fallback
#define PSTR 40          // Psh row stride (shorts): 80B rows, 16B-aligned reads (halves scheme)
#define QSCALE 0.18033688011f   // 0.125 * log2(e)
#define BH_STRIDE (2048*64)     // shorts per bh plane in Kbf / Vtb

// pack two floats -> two bf16 (round-half-up) in one u32
static __device__ __forceinline__ unsigned pkbf(float a, float b) {
    union { float f; unsigned u; } ua, ub; ua.f = a; ub.f = b;
    return ((ua.u + 0x8000u) >> 16) | ((ub.u + 0x8000u) & 0xffff0000u);
}

static __device__ __forceinline__ float fexp2(float x) {
#if __has_builtin(__builtin_amdgcn_exp2f)
    return __builtin_amdgcn_exp2f(x);
#else
    return exp2f(x);
#endif
}

// async global->LDS, 16B per lane; LDS dest = wave-uniform base + lane*16
static __device__ __forceinline__ void gload16(const ushort_t* g, short* l) {
    __builtin_amdgcn_global_load_lds(
        (const __attribute__((address_space(1))) unsigned int*)(g),
        (__attribute__((address_space(3))) unsigned int*)(l), 16, 0, 0);
}

// ---------------- prep: fp32 K,V -> bf16 Kbf[bh][key][d], Vtb[bh][d][key] ----------------
__global__ __launch_bounds__(256)
void prep_bf16(const float* __restrict__ K, const float* __restrict__ V,
               ushort_t* __restrict__ Kbf, ushort_t* __restrict__ Vtb)
{
    __shared__ short Tt[64 * LDSK];
    const int kt = blockIdx.x, bh = blockIdx.y;
    const int t = threadIdx.x;

    // K phase: 64 keys x 64 d, coalesced read, contiguous bf16 write
    {
        const int key = t >> 2, cq = (t & 3) * 16;
        const float* kp = K + (size_t)(kt * 64 + key) * RS + bh * 64 + cq;
        f32x4 a0 = *(const f32x4*)kp,     a1 = *(const f32x4*)(kp + 4);
        f32x4 a2 = *(const f32x4*)(kp + 8), a3 = *(const f32x4*)(kp + 12);
        u32x4 w0, w1;
        w0[0] = pkbf(a0[0], a0[1]); w0[1] = pkbf(a0[2], a0[3]);
        w0[2] = pkbf(a1[0], a1[1]); w0[3] = pkbf(a1[2], a1[3]);
        w1[0] = pkbf(a2[0], a2[1]); w1[1] = pkbf(a2[2], a2[3]);
        w1[2] = pkbf(a3[0], a3[1]); w1[3] = pkbf(a3[2], a3[3]);
        ushort_t* kout = Kbf + (size_t)bh * BH_STRIDE + (size_t)(kt * 64 + key) * 64 + cq;
        *(u32x4*)kout = w0;
        *(u32x4*)(kout + 8) = w1;
    }
    // V phase: transpose 64 keys x 64 d via LDS (key-pairs packed per u32)
    {
        const int vkey = (t & 31) * 2, vd = (t >> 5) * 8;
        const float* vp = V + (size_t)(kt * 64 + vkey) * RS + bh * 64 + vd;
        f32x4 b0 = *(const f32x4*)vp,        b1 = *(const f32x4*)(vp + 4);
        f32x4 c0 = *(const f32x4*)(vp + RS), c1 = *(const f32x4*)(vp + RS + 4);
        #pragma unroll
        for (int i = 0; i < 4; ++i) {
            *(unsigned*)&Tt[(vd + i) * LDSK + vkey]     = pkbf(b0[i], c0[i]);
            *(unsigned*)&Tt[(vd + 4 + i) * LDSK + vkey] = pkbf(b1[i], c1[i]);
        }
    }
    __syncthreads();
    {
        // write-back: 64 d-rows x 64 keys; each thread writes two 16B chunks
        const int d = t >> 2, kq = (t & 3) * 16;
        ushort_t* vout = Vtb + (size_t)bh * BH_STRIDE + (size_t)d * RS + kt * 64 + kq;
        u32x4 w0 = *(const u32x4*)&Tt[d * LDSK + kq];
        u32x4 w1 = *(const u32x4*)&Tt[d * LDSK + kq + 8];
        *(u32x4*)vout = w0;
        *(u32x4*)(vout + 8) = w1;
    }
}

// ---------------- main: flash attention, gload_lds-staged, 1 barrier/tile ----------------
// REVERT to the round-1 harness-verified kernel (passed, fa 42.2-43.0 us).
// Two-group (128 q-rows/wave-pair) variants failed correctness 4x with no
// inspectable cause; this is the best proven-good configuration.
// LDS layout: Kd/Vd are [2][64 rows][8 slots of 8 shorts]; chunk (row, g) of the
// tile (g = d-group for K, key-group for V) lives at slot (g ^ (row&7)).
// gload_lds writes lane-linear, so the XOR is applied to the per-lane GLOBAL
// source address (rule 21: inverse-swizzled source + swizzled read, linear dest).
__global__ __launch_bounds__(256, 4)
void fa_fwd3(const float* __restrict__ Q, const ushort_t* __restrict__ Kbf,
             const ushort_t* __restrict__ Vtb, float* __restrict__ Out)
{
    __shared__ alignas(16) short Kd[2][4096];
    __shared__ alignas(16) short Vd[2][4096];
    __shared__ alignas(16) short Psh[4][16 * PSTR];

    const int x = blockIdx.x;
    const int chunk = x >> 8, idx = x & 255;
    const int bh = idx & 31, s = idx >> 5;
    const int qt = (chunk == 0) ? (31 - s) : (chunk == 1) ? (23 - s)
                 : (chunk == 2) ? s : (8 + s);
    const int base = bh * 64;
    const int tid = threadIdx.x;
    const int wave = tid >> 6;
    const int n15 = tid & 15, quad = (tid & 63) >> 4;
    const int q0 = qt * 64;

    // staging source mapping: thread tid handles tile chunks tid and tid+256.
    // chunk c: row=c>>3, slot=c&7, content group g = slot ^ (row&7).
    const int srow = tid >> 3, sg = (tid & 7) ^ (srow & 7);
    const ushort_t* kb2 = Kbf + (size_t)bh * BH_STRIDE + srow * 64 + sg * 8;
    const ushort_t* vb2 = Vtb + (size_t)bh * BH_STRIDE + (size_t)srow * RS + sg * 8;

    auto stage = [&](int buf, int kt) {
        const ushort_t* ks = kb2 + (size_t)kt * 4096;
        const ushort_t* vs = vb2 + kt * 64;
        short* kd = &Kd[buf][wave * 512];
        short* vd = &Vd[buf][wave * 512];
        gload16(ks,         kd);
        gload16(ks + 2048,  kd + 2048);   // rows +32 -> chunks +256
        gload16(vs,         vd);
        gload16(vs + 65536, vd + 2048);   // d +32 (32*RS shorts)
    };

    stage(0, 0);   // tile-0 loads in flight while we set up Q

    // Q fragment (B operand of S^T = K.Q^T), pre-scaled into log2 domain
    bf16x8 qf[2];
    {
        const float* qp = Q + (size_t)(q0 + wave * 16 + n15) * RS + base + quad * 8;
        #pragma unroll
        for (int ks = 0; ks < 2; ++ks) {
            f32x4 a0 = *(const f32x4*)(qp + ks * 32) * QSCALE;
            f32x4 a1 = *(const f32x4*)(qp + ks * 32 + 4) * QSCALE;
            union { u32x4 u; bf16x8 s; } w;
            w.u[0] = pkbf(a0[0], a0[1]); w.u[1] = pkbf(a0[2], a0[3]);
            w.u[2] = pkbf(a1[0], a1[1]); w.u[3] = pkbf(a1[2], a1[3]);
            qf[ks] = w.s;
        }
    }

    f32x4 O[4];
    #pragma unroll
    for (int i = 0; i < 4; ++i) O[i] = (f32x4){0.f, 0.f, 0.f, 0.f};
    float l = 0.f;

    // swizzled ds_read column offsets (shorts): (quad*8) ^ ((n15&7)*8), second half ^32
    const int c0 = (quad * 8) ^ ((n15 & 7) * 8);
    const int c1 = c0 ^ 32;

    asm volatile("s_waitcnt vmcnt(0)" ::: "memory");
    __builtin_amdgcn_sched_barrier(0);
    __builtin_amdgcn_s_barrier();

    int buf = 0;
    for (int kt = 0; kt <= qt; ++kt) {
        if (kt < qt) stage(buf ^ 1, kt + 1);   // async loads fly under compute
        const short* Kb_ = Kd[buf];
        const short* Vb_ = Vd[buf];

        // QK^T -> S^T tile: row = key = mb*16+quad*4+r, col = q = n15
        f32x4 S[4];
        __builtin_amdgcn_s_setprio(1);
        #pragma unroll
        for (int mb = 0; mb < 4; ++mb) {
            const short* kr = Kb_ + (mb * 16 + n15) * 64;
            bf16x8 kf0 = *(const bf16x8*)(kr + c0);
            bf16x8 kf1 = *(const bf16x8*)(kr + c1);
            f32x4 sv = (f32x4){0.f, 0.f, 0.f, 0.f};
            sv = __builtin_amdgcn_mfma_f32_16x16x32_bf16(kf0, qf[0], sv, 0, 0, 0);
            sv = __builtin_amdgcn_mfma_f32_16x16x32_bf16(kf1, qf[1], sv, 0, 0, 0);
            S[mb] = sv;
        }
        __builtin_amdgcn_s_setprio(0);

        if (kt == qt) {
            const int kb_ = kt * 64;
            const int q = q0 + wave * 16 + n15;
            #pragma unroll
            for (int mb = 0; mb < 4; ++mb)
                #pragma unroll
                for (int r = 0; r < 4; ++r)
                    if (kb_ + mb * 16 + quad * 4 + r > q) S[mb][r] = -1e30f;
        }

        // softmax + P staging per 32-key half (Psh half-size, reused across halves;
        // DS ops are in-order per wave so the pf read of half 0 completes before
        // half 1's overwrite)
        float rs = 0.f;
        bf16x8 pf[2];
        #pragma unroll
        for (int half = 0; half < 2; ++half) {
            #pragma unroll
            for (int m2 = 0; m2 < 2; ++m2) {
                f32x4 sv = S[half * 2 + m2];
                float p0 = fexp2(sv[0]), p1 = fexp2(sv[1]);
                float p2 = fexp2(sv[2]), p3 = fexp2(sv[3]);
                rs += (p0 + p1) + (p2 + p3);
                unsigned w0, w1;
                asm("v_cvt_pk_bf16_f32 %0, %1, %2" : "=v"(w0) : "v"(p0), "v"(p1));
                asm("v_cvt_pk_bf16_f32 %0, %1, %2" : "=v"(w1) : "v"(p2), "v"(p3));
                u32x2 w; w[0] = w0; w[1] = w1;
                *(u32x2*)&Psh[wave][n15 * PSTR + m2 * 16 + quad * 4] = w;
            }
            pf[half] = *(const bf16x8*)&Psh[wave][n15 * PSTR + quad * 8];
        }
        rs += __shfl_xor(rs, 16);
        rs += __shfl_xor(rs, 32);
        l += rs;

        // PV: O[q][d] += P[q][keys] * V^T[d][keys]
        __builtin_amdgcn_s_setprio(1);
        #pragma unroll
        for (int db = 0; db < 4; ++db) {
            const short* vr = Vb_ + (db * 16 + n15) * 64;
            bf16x8 vf0 = *(const bf16x8*)(vr + c0);
            O[db] = __builtin_amdgcn_mfma_f32_16x16x32_bf16(pf[0], vf0, O[db], 0, 0, 0);
            bf16x8 vf1 = *(const bf16x8*)(vr + c1);
            O[db] = __builtin_amdgcn_mfma_f32_16x16x32_bf16(pf[1], vf1, O[db], 0, 0, 0);
        }
        __builtin_amdgcn_s_setprio(0);

        if (kt < qt) {
            // next buffer fully loaded + everyone done reading current buffer:
            // the ONLY barrier in the tile loop (raw, no compiler-forced drain order)
            asm volatile("s_waitcnt vmcnt(0)" ::: "memory");
            __builtin_amdgcn_sched_barrier(0);
            __builtin_amdgcn_s_barrier();
            buf ^= 1;
        }
    }

    #pragma unroll
    for (int r = 0; r < 4; ++r) {
        float inv = 1.0f / __shfl(l, quad * 4 + r);
        size_t row = (size_t)(q0 + wave * 16 + quad * 4 + r) * RS + base;
        #pragma unroll
        for (int db = 0; db < 4; ++db)
            Out[row + db * 16 + n15] = O[db][r] * inv;
    }
}

// ---------------- fallback (round-6 kernel) if ws is too small ----------------
__global__ __launch_bounds__(256, 3)
void fa_fwd_fb(const float* __restrict__ Q, const float* __restrict__ K,
               const float* __restrict__ V, float* __restrict__ Out)
{
    __shared__ short Ksh[2][64 * LDSK];
    __shared__ short Vt[2][64 * LDSK];
    __shared__ short Psh[4][16 * LDSK];

    const int qt = 31 - blockIdx.y;
    const int bh = blockIdx.x;
    const int base = bh * 64;
    const int tid = threadIdx.x;
    const int wave = tid >> 6, lane = tid & 63;
    const int n15 = lane & 15, quad = lane >> 4;
    const int q0 = qt * 64;
    const int krow = tid >> 2, kcg = (tid & 3) * 16;
    const int vkey = (tid & 31) * 2, vd = (tid >> 5) * 4;

    bf16x8 qf[2];
    {
        const float* qp = Q + (size_t)(q0 + wave * 16 + n15) * RS + base + quad * 8;
        #pragma unroll
        for (int ks = 0; ks < 2; ++ks) {
            f32x4 a0 = *(const f32x4*)(qp + ks * 32) * QSCALE;
            f32x4 a1 = *(const f32x4*)(qp + ks * 32 + 4) * QSCALE;
            union { u32x4 u; bf16x8 s; } w;
            w.u[0] = pkbf(a0[0], a0[1]); w.u[1] = pkbf(a0[2], a0[3]);
            w.u[2] = pkbf(a1[0], a1[1]); w.u[3] = pkbf(a1[2], a1[3]);
            qf[ks] = w.s;
        }
    }
    f32x4 O[4];
    #pragma unroll
    for (int i = 0; i < 4; ++i) O[i] = (f32x4){0.f, 0.f, 0.f, 0.f};
    float l = 0.f;
    f32x4 rk0, rk1, rk2, rk3, rv0, rv1, rv2, rv3;
    auto prefetch = [&](int kt) {
        const int kb = kt * 64;
        const float* kp = K + (size_t)(kb + krow) * RS + base + kcg;
        rk0 = *(const f32x4*)kp;       rk1 = *(const f32x4*)(kp + 4);
        rk2 = *(const f32x4*)(kp + 8); rk3 = *(const f32x4*)(kp + 12);
        const float* vp = V + (size_t)(kb + vkey) * RS + base + vd;
        rv0 = *(const f32x4*)vp;        rv1 = *(const f32x4*)(vp + RS);
        rv2 = *(const f32x4*)(vp + 32); rv3 = *(const f32x4*)(vp + RS + 32);
    };
    auto stage = [&](int buf) {
        u32x4 w0; w0[0] = pkbf(rk0[0], rk0[1]); w0[1] = pkbf(rk0[2], rk0[3]);
                  w0[2] = pkbf(rk1[0], rk1[1]); w0[3] = pkbf(rk1[2], rk1[3]);
        *(u32x4*)&Ksh[buf][krow * LDSK + kcg] = w0;
        u32x4 w1; w1[0] = pkbf(rk2[0], rk2[1]); w1[1] = pkbf(rk2[2], rk2[3]);
                  w1[2] = pkbf(rk3[0], rk3[1]); w1[3] = pkbf(rk3[2], rk3[3]);
        *(u32x4*)&Ksh[buf][krow * LDSK + kcg + 8] = w1;
        #pragma unroll
        for (int i = 0; i < 4; ++i) {
            *(unsigned*)&Vt[buf][(vd + i) * LDSK + vkey] = pkbf(rv0[i], rv1[i]);
            *(unsigned*)&Vt[buf][(vd + 32 + i) * LDSK + vkey] = pkbf(rv2[i], rv3[i]);
        }
    };
    auto compute = [&](int buf, int kb, bool diag) {
        f32x4 S[4];
        #pragma unroll
        for (int mb = 0; mb < 4; ++mb) {
            f32x4 sv = (f32x4){0.f, 0.f, 0.f, 0.f};
            bf16x8 kf0 = *(const bf16x8*)&Ksh[buf][(mb * 16 + n15) * LDSK + quad * 8];
            sv = __builtin_amdgcn_mfma_f32_16x16x32_bf16(kf0, qf[0], sv, 0, 0, 0);
            bf16x8 kf1 = *(const bf16x8*)&Ksh[buf][(mb * 16 + n15) * LDSK + 32 + quad * 8];
            sv = __builtin_amdgcn_mfma_f32_16x16x32_bf16(kf1, qf[1], sv, 0, 0, 0);
            S[mb] = sv;
        }
        if (diag) {
            int q = q0 + wave * 16 + n15;
            #pragma unroll
            for (int mb = 0; mb < 4; ++mb)
                #pragma unroll
                for (int r = 0; r < 4; ++r)
                    if (kb + mb * 16 + quad * 4 + r > q) S[mb][r] = -1e30f;
        }
        float rs = 0.f;
        #pragma unroll
        for (int mb = 0; mb < 4; ++mb) {
            float p0 = fexp2(S[mb][0]), p1 = fexp2(S[mb][1]);
            float p2 = fexp2(S[mb][2]), p3 = fexp2(S[mb][3]);
            rs += (p0 + p1) + (p2 + p3);
            u32x2 w; w[0] = pkbf(p0, p1); w[1] = pkbf(p2, p3);
            *(u32x2*)&Psh[wave][n15 * LDSK + mb * 16 + quad * 4] = w;
        }
        rs += __shfl_xor(rs, 16);
        rs += __shfl_xor(rs, 32);
        l += rs;
        bf16x8 pf0 = *(const bf16x8*)&Psh[wave][n15 * LDSK + quad * 8];
        bf16x8 pf1 = *(const bf16x8*)&Psh[wave][n15 * LDSK + 32 + quad * 8];
        #pragma unroll
        for (int db = 0; db < 4; ++db) {
            bf16x8 vf0 = *(const bf16x8*)&Vt[buf][(db * 16 + n15) * LDSK + quad * 8];
            O[db] = __builtin_amdgcn_mfma_f32_16x16x32_bf16(pf0, vf0, O[db], 0, 0, 0);
            bf16x8 vf1 = *(const bf16x8*)&Vt[buf][(db * 16 + n15) * LDSK + 32 + quad * 8];
            O[db] = __builtin_amdgcn_mfma_f32_16x16x32_bf16(pf1, vf1, O[db], 0, 0, 0);
        }
    };
    prefetch(0);
    stage(0);
    __syncthreads();
    for (int kt = 0; kt <= qt; ++kt) {
        const int cur = kt & 1;
        if (kt < qt) prefetch(kt + 1);
        compute(cur, kt * 64, kt == qt);
        if (kt < qt) stage(1 - cur);
        __syncthreads();
    }
    #pragma unroll
    for (int r = 0; r < 4; ++r) {
        float inv = 1.0f / __shfl(l, quad * 4 + r);
        size_t row = (size_t)(q0 + wave * 16 + quad * 4 + r) * RS + base;
        #pragma unroll
        for (int db = 0; db < 4; ++db)
            Out[row + db * 16 + n15] = O[db][r] * inv;
    }
}

extern "C" void kernel_launch(void* const* d_in, const int* in_sizes, int n_in,
                              void* d_out, int out_size, void* d_ws, size_t ws_size,
                              hipStream_t stream) {
    const float* Q = (const float*)d_in[0];
    const float* K = (const float*)d_in[1];
    const float* V = (const float*)d_in[2];
    float* Out = (float*)d_out;

    if (ws_size >= (size_t)2 * 32 * BH_STRIDE * sizeof(ushort_t)) {
        ushort_t* Kbf = (ushort_t*)d_ws;
        ushort_t* Vtb = Kbf + (size_t)32 * BH_STRIDE;
        prep_bf16<<<dim3(32, 32), dim3(256), 0, stream>>>(K, V, Kbf, Vtb);
        fa_fwd3<<<dim3(1024), dim3(256), 0, stream>>>(Q, Kbf, Vtb, Out);
    } else {
        fa_fwd_fb<<<dim3(32, 32), dim3(256), 0, stream>>>(Q, K, V, Out);
    }
}

// Round 9
// 140.503 us; speedup vs baseline: 1.0827x; 1.0020x over previous
//
#include <hip/hip_runtime.h>

typedef short bf16x8 __attribute__((ext_vector_type(8)));
typedef float f32x4 __attribute__((ext_vector_type(4)));
typedef unsigned u32x4 __attribute__((ext_vector_type(4)));
typedef unsigned u32x2 __attribute__((ext_vector_type(2)));
typedef unsigned short ushort_t;

#define RS 2048          // fp32 tensor row stride (elements)
#define LDSK 72          // padded LDS row stride (shorts) for prep/fallback
#define PSTR 56          // Psh row stride (shorts): 112B rows (7x16B): bank=(28*n15+2*q)%32,
                         // only a single 2-way alias class (free, m136) vs PSTR=40's 4-way groups
#define QSCALE 0.18033688011f   // 0.125 * log2(e)
#define BH_STRIDE (2048*64)     // shorts per bh plane in Kbf / Vtb

// pack two floats -> two bf16 (round-half-up) in one u32
static __device__ __forceinline__ unsigned pkbf(float a, float b) {
    union { float f; unsigned u; } ua, ub; ua.f = a; ub.f = b;
    return ((ua.u + 0x8000u) >> 16) | ((ub.u + 0x8000u) & 0xffff0000u);
}

static __device__ __forceinline__ float fexp2(float x) {
#if __has_builtin(__builtin_amdgcn_exp2f)
    return __builtin_amdgcn_exp2f(x);
#else
    return exp2f(x);
#endif
}

// async global->LDS, 16B per lane; LDS dest = wave-uniform base + lane*16
static __device__ __forceinline__ void gload16(const ushort_t* g, short* l) {
    __builtin_amdgcn_global_load_lds(
        (const __attribute__((address_space(1))) unsigned int*)(g),
        (__attribute__((address_space(3))) unsigned int*)(l), 16, 0, 0);
}

// ---------------- prep: fp32 K,V -> bf16 Kbf[bh][key][d], Vtb[bh][d][key] ----------------
__global__ __launch_bounds__(256)
void prep_bf16(const float* __restrict__ K, const float* __restrict__ V,
               ushort_t* __restrict__ Kbf, ushort_t* __restrict__ Vtb)
{
    __shared__ short Tt[64 * LDSK];
    const int kt = blockIdx.x, bh = blockIdx.y;
    const int t = threadIdx.x;

    // K phase: 64 keys x 64 d, coalesced read, contiguous bf16 write
    {
        const int key = t >> 2, cq = (t & 3) * 16;
        const float* kp = K + (size_t)(kt * 64 + key) * RS + bh * 64 + cq;
        f32x4 a0 = *(const f32x4*)kp,     a1 = *(const f32x4*)(kp + 4);
        f32x4 a2 = *(const f32x4*)(kp + 8), a3 = *(const f32x4*)(kp + 12);
        u32x4 w0, w1;
        w0[0] = pkbf(a0[0], a0[1]); w0[1] = pkbf(a0[2], a0[3]);
        w0[2] = pkbf(a1[0], a1[1]); w0[3] = pkbf(a1[2], a1[3]);
        w1[0] = pkbf(a2[0], a2[1]); w1[1] = pkbf(a2[2], a2[3]);
        w1[2] = pkbf(a3[0], a3[1]); w1[3] = pkbf(a3[2], a3[3]);
        ushort_t* kout = Kbf + (size_t)bh * BH_STRIDE + (size_t)(kt * 64 + key) * 64 + cq;
        *(u32x4*)kout = w0;
        *(u32x4*)(kout + 8) = w1;
    }
    // V phase: transpose 64 keys x 64 d via LDS (key-pairs packed per u32)
    {
        const int vkey = (t & 31) * 2, vd = (t >> 5) * 8;
        const float* vp = V + (size_t)(kt * 64 + vkey) * RS + bh * 64 + vd;
        f32x4 b0 = *(const f32x4*)vp,        b1 = *(const f32x4*)(vp + 4);
        f32x4 c0 = *(const f32x4*)(vp + RS), c1 = *(const f32x4*)(vp + RS + 4);
        #pragma unroll
        for (int i = 0; i < 4; ++i) {
            *(unsigned*)&Tt[(vd + i) * LDSK + vkey]     = pkbf(b0[i], c0[i]);
            *(unsigned*)&Tt[(vd + 4 + i) * LDSK + vkey] = pkbf(b1[i], c1[i]);
        }
    }
    __syncthreads();
    {
        // write-back: 64 d-rows x 64 keys; each thread writes two 16B chunks
        const int d = t >> 2, kq = (t & 3) * 16;
        ushort_t* vout = Vtb + (size_t)bh * BH_STRIDE + (size_t)d * RS + kt * 64 + kq;
        u32x4 w0 = *(const u32x4*)&Tt[d * LDSK + kq];
        u32x4 w1 = *(const u32x4*)&Tt[d * LDSK + kq + 8];
        *(u32x4*)vout = w0;
        *(u32x4*)(vout + 8) = w1;
    }
}

// ---------------- main: flash attention, gload_lds-staged, 1 barrier/tile ----------------
// Round-1-verified structure; only change vs r8: PSTR 40 -> 56 to spread the Psh
// write banks (the source of the 1.6M SQ_LDS_BANK_CONFLICT cycles).
// LDS layout: Kd/Vd are [2][64 rows][8 slots of 8 shorts]; chunk (row, g) of the
// tile (g = d-group for K, key-group for V) lives at slot (g ^ (row&7)).
// gload_lds writes lane-linear, so the XOR is applied to the per-lane GLOBAL
// source address (rule 21: inverse-swizzled source + swizzled read, linear dest).
__global__ __launch_bounds__(256, 4)
void fa_fwd3(const float* __restrict__ Q, const ushort_t* __restrict__ Kbf,
             const ushort_t* __restrict__ Vtb, float* __restrict__ Out)
{
    __shared__ alignas(16) short Kd[2][4096];
    __shared__ alignas(16) short Vd[2][4096];
    __shared__ alignas(16) short Psh[4][16 * PSTR];

    const int x = blockIdx.x;
    const int chunk = x >> 8, idx = x & 255;
    const int bh = idx & 31, s = idx >> 5;
    const int qt = (chunk == 0) ? (31 - s) : (chunk == 1) ? (23 - s)
                 : (chunk == 2) ? s : (8 + s);
    const int base = bh * 64;
    const int tid = threadIdx.x;
    const int wave = tid >> 6;
    const int n15 = tid & 15, quad = (tid & 63) >> 4;
    const int q0 = qt * 64;

    // staging source mapping: thread tid handles tile chunks tid and tid+256.
    // chunk c: row=c>>3, slot=c&7, content group g = slot ^ (row&7).
    const int srow = tid >> 3, sg = (tid & 7) ^ (srow & 7);
    const ushort_t* kb2 = Kbf + (size_t)bh * BH_STRIDE + srow * 64 + sg * 8;
    const ushort_t* vb2 = Vtb + (size_t)bh * BH_STRIDE + (size_t)srow * RS + sg * 8;

    auto stage = [&](int buf, int kt) {
        const ushort_t* ks = kb2 + (size_t)kt * 4096;
        const ushort_t* vs = vb2 + kt * 64;
        short* kd = &Kd[buf][wave * 512];
        short* vd = &Vd[buf][wave * 512];
        gload16(ks,         kd);
        gload16(ks + 2048,  kd + 2048);   // rows +32 -> chunks +256
        gload16(vs,         vd);
        gload16(vs + 65536, vd + 2048);   // d +32 (32*RS shorts)
    };

    stage(0, 0);   // tile-0 loads in flight while we set up Q

    // Q fragment (B operand of S^T = K.Q^T), pre-scaled into log2 domain
    bf16x8 qf[2];
    {
        const float* qp = Q + (size_t)(q0 + wave * 16 + n15) * RS + base + quad * 8;
        #pragma unroll
        for (int ks = 0; ks < 2; ++ks) {
            f32x4 a0 = *(const f32x4*)(qp + ks * 32) * QSCALE;
            f32x4 a1 = *(const f32x4*)(qp + ks * 32 + 4) * QSCALE;
            union { u32x4 u; bf16x8 s; } w;
            w.u[0] = pkbf(a0[0], a0[1]); w.u[1] = pkbf(a0[2], a0[3]);
            w.u[2] = pkbf(a1[0], a1[1]); w.u[3] = pkbf(a1[2], a1[3]);
            qf[ks] = w.s;
        }
    }

    f32x4 O[4];
    #pragma unroll
    for (int i = 0; i < 4; ++i) O[i] = (f32x4){0.f, 0.f, 0.f, 0.f};
    float l = 0.f;

    // swizzled ds_read column offsets (shorts): (quad*8) ^ ((n15&7)*8), second half ^32
    const int c0 = (quad * 8) ^ ((n15 & 7) * 8);
    const int c1 = c0 ^ 32;

    asm volatile("s_waitcnt vmcnt(0)" ::: "memory");
    __builtin_amdgcn_sched_barrier(0);
    __builtin_amdgcn_s_barrier();

    int buf = 0;
    for (int kt = 0; kt <= qt; ++kt) {
        if (kt < qt) stage(buf ^ 1, kt + 1);   // async loads fly under compute
        const short* Kb_ = Kd[buf];
        const short* Vb_ = Vd[buf];

        // QK^T -> S^T tile: row = key = mb*16+quad*4+r, col = q = n15
        f32x4 S[4];
        __builtin_amdgcn_s_setprio(1);
        #pragma unroll
        for (int mb = 0; mb < 4; ++mb) {
            const short* kr = Kb_ + (mb * 16 + n15) * 64;
            bf16x8 kf0 = *(const bf16x8*)(kr + c0);
            bf16x8 kf1 = *(const bf16x8*)(kr + c1);
            f32x4 sv = (f32x4){0.f, 0.f, 0.f, 0.f};
            sv = __builtin_amdgcn_mfma_f32_16x16x32_bf16(kf0, qf[0], sv, 0, 0, 0);
            sv = __builtin_amdgcn_mfma_f32_16x16x32_bf16(kf1, qf[1], sv, 0, 0, 0);
            S[mb] = sv;
        }
        __builtin_amdgcn_s_setprio(0);

        if (kt == qt) {
            const int kb_ = kt * 64;
            const int q = q0 + wave * 16 + n15;
            #pragma unroll
            for (int mb = 0; mb < 4; ++mb)
                #pragma unroll
                for (int r = 0; r < 4; ++r)
                    if (kb_ + mb * 16 + quad * 4 + r > q) S[mb][r] = -1e30f;
        }

        // softmax + P staging per 32-key half (Psh half-size, reused across halves;
        // DS ops are in-order per wave so the pf read of half 0 completes before
        // half 1's overwrite)
        float rs = 0.f;
        bf16x8 pf[2];
        #pragma unroll
        for (int half = 0; half < 2; ++half) {
            #pragma unroll
            for (int m2 = 0; m2 < 2; ++m2) {
                f32x4 sv = S[half * 2 + m2];
                float p0 = fexp2(sv[0]), p1 = fexp2(sv[1]);
                float p2 = fexp2(sv[2]), p3 = fexp2(sv[3]);
                rs += (p0 + p1) + (p2 + p3);
                unsigned w0, w1;
                asm("v_cvt_pk_bf16_f32 %0, %1, %2" : "=v"(w0) : "v"(p0), "v"(p1));
                asm("v_cvt_pk_bf16_f32 %0, %1, %2" : "=v"(w1) : "v"(p2), "v"(p3));
                u32x2 w; w[0] = w0; w[1] = w1;
                *(u32x2*)&Psh[wave][n15 * PSTR + m2 * 16 + quad * 4] = w;
            }
            pf[half] = *(const bf16x8*)&Psh[wave][n15 * PSTR + quad * 8];
        }
        rs += __shfl_xor(rs, 16);
        rs += __shfl_xor(rs, 32);
        l += rs;

        // PV: O[q][d] += P[q][keys] * V^T[d][keys]
        __builtin_amdgcn_s_setprio(1);
        #pragma unroll
        for (int db = 0; db < 4; ++db) {
            const short* vr = Vb_ + (db * 16 + n15) * 64;
            bf16x8 vf0 = *(const bf16x8*)(vr + c0);
            O[db] = __builtin_amdgcn_mfma_f32_16x16x32_bf16(pf[0], vf0, O[db], 0, 0, 0);
            bf16x8 vf1 = *(const bf16x8*)(vr + c1);
            O[db] = __builtin_amdgcn_mfma_f32_16x16x32_bf16(pf[1], vf1, O[db], 0, 0, 0);
        }
        __builtin_amdgcn_s_setprio(0);

        if (kt < qt) {
            // next buffer fully loaded + everyone done reading current buffer:
            // the ONLY barrier in the tile loop (raw, no compiler-forced drain order)
            asm volatile("s_waitcnt vmcnt(0)" ::: "memory");
            __builtin_amdgcn_sched_barrier(0);
            __builtin_amdgcn_s_barrier();
            buf ^= 1;
        }
    }

    #pragma unroll
    for (int r = 0; r < 4; ++r) {
        float inv = 1.0f / __shfl(l, quad * 4 + r);
        size_t row = (size_t)(q0 + wave * 16 + quad * 4 + r) * RS + base;
        #pragma unroll
        for (int db = 0; db < 4; ++db)
            Out[row + db * 16 + n15] = O[db][r] * inv;
    }
}

// ---------------- fallback (round-6 kernel) if ws is too small ----------------
__global__ __launch_bounds__(256, 3)
void fa_fwd_fb(const float* __restrict__ Q, const float* __restrict__ K,
               const float* __restrict__ V, float* __restrict__ Out)
{
    __shared__ short Ksh[2][64 * LDSK];
    __shared__ short Vt[2][64 * LDSK];
    __shared__ short Psh[4][16 * LDSK];

    const int qt = 31 - blockIdx.y;
    const int bh = blockIdx.x;
    const int base = bh * 64;
    const int tid = threadIdx.x;
    const int wave = tid >> 6, lane = tid & 63;
    const int n15 = lane & 15, quad = lane >> 4;
    const int q0 = qt * 64;
    const int krow = tid >> 2, kcg = (tid & 3) * 16;
    const int vkey = (tid & 31) * 2, vd = (tid >> 5) * 4;

    bf16x8 qf[2];
    {
        const float* qp = Q + (size_t)(q0 + wave * 16 + n15) * RS + base + quad * 8;
        #pragma unroll
        for (int ks = 0; ks < 2; ++ks) {
            f32x4 a0 = *(const f32x4*)(qp + ks * 32) * QSCALE;
            f32x4 a1 = *(const f32x4*)(qp + ks * 32 + 4) * QSCALE;
            union { u32x4 u; bf16x8 s; } w;
            w.u[0] = pkbf(a0[0], a0[1]); w.u[1] = pkbf(a0[2], a0[3]);
            w.u[2] = pkbf(a1[0], a1[1]); w.u[3] = pkbf(a1[2], a1[3]);
            qf[ks] = w.s;
        }
    }
    f32x4 O[4];
    #pragma unroll
    for (int i = 0; i < 4; ++i) O[i] = (f32x4){0.f, 0.f, 0.f, 0.f};
    float l = 0.f;
    f32x4 rk0, rk1, rk2, rk3, rv0, rv1, rv2, rv3;
    auto prefetch = [&](int kt) {
        const int kb = kt * 64;
        const float* kp = K + (size_t)(kb + krow) * RS + base + kcg;
        rk0 = *(const f32x4*)kp;       rk1 = *(const f32x4*)(kp + 4);
        rk2 = *(const f32x4*)(kp + 8); rk3 = *(const f32x4*)(kp + 12);
        const float* vp = V + (size_t)(kb + vkey) * RS + base + vd;
        rv0 = *(const f32x4*)vp;        rv1 = *(const f32x4*)(vp + RS);
        rv2 = *(const f32x4*)(vp + 32); rv3 = *(const f32x4*)(vp + RS + 32);
    };
    auto stage = [&](int buf) {
        u32x4 w0; w0[0] = pkbf(rk0[0], rk0[1]); w0[1] = pkbf(rk0[2], rk0[3]);
                  w0[2] = pkbf(rk1[0], rk1[1]); w0[3] = pkbf(rk1[2], rk1[3]);
        *(u32x4*)&Ksh[buf][krow * LDSK + kcg] = w0;
        u32x4 w1; w1[0] = pkbf(rk2[0], rk2[1]); w1[1] = pkbf(rk2[2], rk2[3]);
                  w1[2] = pkbf(rk3[0], rk3[1]); w1[3] = pkbf(rk3[2], rk3[3]);
        *(u32x4*)&Ksh[buf][krow * LDSK + kcg + 8] = w1;
        #pragma unroll
        for (int i = 0; i < 4; ++i) {
            *(unsigned*)&Vt[buf][(vd + i) * LDSK + vkey] = pkbf(rv0[i], rv1[i]);
            *(unsigned*)&Vt[buf][(vd + 32 + i) * LDSK + vkey] = pkbf(rv2[i], rv3[i]);
        }
    };
    auto compute = [&](int buf, int kb, bool diag) {
        f32x4 S[4];
        #pragma unroll
        for (int mb = 0; mb < 4; ++mb) {
            f32x4 sv = (f32x4){0.f, 0.f, 0.f, 0.f};
            bf16x8 kf0 = *(const bf16x8*)&Ksh[buf][(mb * 16 + n15) * LDSK + quad * 8];
            sv = __builtin_amdgcn_mfma_f32_16x16x32_bf16(kf0, qf[0], sv, 0, 0, 0);
            bf16x8 kf1 = *(const bf16x8*)&Ksh[buf][(mb * 16 + n15) * LDSK + 32 + quad * 8];
            sv = __builtin_amdgcn_mfma_f32_16x16x32_bf16(kf1, qf[1], sv, 0, 0, 0);
            S[mb] = sv;
        }
        if (diag) {
            int q = q0 + wave * 16 + n15;
            #pragma unroll
            for (int mb = 0; mb < 4; ++mb)
                #pragma unroll
                for (int r = 0; r < 4; ++r)
                    if (kb + mb * 16 + quad * 4 + r > q) S[mb][r] = -1e30f;
        }
        float rs = 0.f;
        #pragma unroll
        for (int mb = 0; mb < 4; ++mb) {
            float p0 = fexp2(S[mb][0]), p1 = fexp2(S[mb][1]);
            float p2 = fexp2(S[mb][2]), p3 = fexp2(S[mb][3]);
            rs += (p0 + p1) + (p2 + p3);
            u32x2 w; w[0] = pkbf(p0, p1); w[1] = pkbf(p2, p3);
            *(u32x2*)&Psh[wave][n15 * LDSK + mb * 16 + quad * 4] = w;
        }
        rs += __shfl_xor(rs, 16);
        rs += __shfl_xor(rs, 32);
        l += rs;
        bf16x8 pf0 = *(const bf16x8*)&Psh[wave][n15 * LDSK + quad * 8];
        bf16x8 pf1 = *(const bf16x8*)&Psh[wave][n15 * LDSK + 32 + quad * 8];
        #pragma unroll
        for (int db = 0; db < 4; ++db) {
            bf16x8 vf0 = *(const bf16x8*)&Vt[buf][(db * 16 + n15) * LDSK + quad * 8];
            O[db] = __builtin_amdgcn_mfma_f32_16x16x32_bf16(pf0, vf0, O[db], 0, 0, 0);
            bf16x8 vf1 = *(const bf16x8*)&Vt[buf][(db * 16 + n15) * LDSK + 32 + quad * 8];
            O[db] = __builtin_amdgcn_mfma_f32_16x16x32_bf16(pf1, vf1, O[db], 0, 0, 0);
        }
    };
    prefetch(0);
    stage(0);
    __syncthreads();
    for (int kt = 0; kt <= qt; ++kt) {
        const int cur = kt & 1;
        if (kt < qt) prefetch(kt + 1);
        compute(cur, kt * 64, kt == qt);
        if (kt < qt) stage(1 - cur);
        __syncthreads();
    }
    #pragma unroll
    for (int r = 0; r < 4; ++r) {
        float inv = 1.0f / __shfl(l, quad * 4 + r);
        size_t row = (size_t)(q0 + wave * 16 + quad * 4 + r) * RS + base;
        #pragma unroll
        for (int db = 0; db < 4; ++db)
            Out[row + db * 16 + n15] = O[db][r] * inv;
    }
}

extern "C" void kernel_launch(void* const* d_in, const int* in_sizes, int n_in,
                              void* d_out, int out_size, void* d_ws, size_t ws_size,
                              hipStream_t stream) {
    const float* Q = (const float*)d_in[0];
    const float* K = (const float*)d_in[1];
    const float* V = (const float*)d_in[2];
    float* Out = (float*)d_out;

    if (ws_size >= (size_t)2 * 32 * BH_STRIDE * sizeof(ushort_t)) {
        ushort_t* Kbf = (ushort_t*)d_ws;
        ushort_t* Vtb = Kbf + (size_t)32 * BH_STRIDE;
        prep_bf16<<<dim3(32, 32), dim3(256), 0, stream>>>(K, V, Kbf, Vtb);
        fa_fwd3<<<dim3(1024), dim3(256), 0, stream>>>(Q, Kbf, Vtb, Out);
    } else {
        fa_fwd_fb<<<dim3(32, 32), dim3(256), 0, stream>>>(Q, K, V, Out);
    }
}